// Round 11
// baseline (233.257 us; speedup 1.0000x reference)
//
#include <hip/hip_runtime.h>
#include <math.h>

#define NB_B 16
#define NB_S 4096
#define NB_D 64
#define NB_H 8

// LDS strides (in halfs) chosen so rows are 16B-aligned: 72*2=144=16*9,
// 136*2=272=16*17 -> every MFMA fragment is a single ds_read_b128.
#define KSTR 72
#define PSTR 136
#define VSTR 72

typedef _Float16 half_t;
typedef __attribute__((ext_vector_type(2))) _Float16 half2t;
typedef __attribute__((ext_vector_type(4))) _Float16 half4;
typedef __attribute__((ext_vector_type(8))) _Float16 half8;
typedef __attribute__((ext_vector_type(4))) float floatx4;
typedef __attribute__((ext_vector_type(2))) float float2v;

// ---------------- Kernel 0: precompute fp16 k-hat, v, f32 norm ----------------
// grid: B*S*16/256 blocks; 16 lanes per row. q = norm * khat (Q never stored).
__global__ __launch_bounds__(256) void prep_kernel(const float* __restrict__ qk,
                                                   const float* __restrict__ v,
                                                   half_t* __restrict__ khat,
                                                   half_t* __restrict__ vh,
                                                   float* __restrict__ norm) {
  int g = blockIdx.x * 256 + threadIdx.x;  // over B*S*16
  float4 qv = ((const float4*)qk)[g];
  float4 vv = ((const float4*)v)[g];
  float ss = qv.x * qv.x + qv.y * qv.y + qv.z * qv.z + qv.w * qv.w;
  for (int off = 1; off < 16; off <<= 1) ss += __shfl_xor(ss, off);
  float nr = fmaxf(sqrtf(ss), 1e-12f);
  float sc = 1.0f / nr;
  half4 hk = {(half_t)(qv.x * sc), (half_t)(qv.y * sc), (half_t)(qv.z * sc),
              (half_t)(qv.w * sc)};
  half4 hv = {(half_t)vv.x, (half_t)vv.y, (half_t)vv.z, (half_t)vv.w};
  ((half4*)khat)[g] = hk;
  ((half4*)vh)[g] = hv;
  if ((threadIdx.x & 15) == 0) norm[g >> 4] = nr;
}

// ---------------- Kernel 1: LSH hashing (buckets) ----------------
// Bit-faithful mimic of naive np.einsum float32: each (token, bucket) sum is
// computed by ONE thread in the reference order (fq outer, fi inner, f
// ascending, separate RN mul+add via v_pk) -> sums bit-identical. Argmax is
// local-scan + cross-lane merge with first-max-wins tie-break -> decisions
// bit-identical to jnp.argmax.
// v10: COOPERATIVE BUCKET SPLIT. Ledger R0-R10: hash ~90us vs 14us VALU
// floor; every variant shared the flaw that all 64 lanes re-read the whole
// 8KB rot panel from LDS (128 broadcast ds_read_b128/wave/fc ~= 41us of
// LDS-pipe chip-wide + latency). Now lane=(slot s=lane&7, group gi=lane>>3):
// group gi owns buckets 4gi..4gi+3; per (fi,round) ONE b128 per group ->
// 16 reads/fc/wave (8x cut, conflict-free: 8 distinct 16B chunks = 32 banks).
// 8 tokens/thread: acc 32 pairs (64 VGPR) + q4[8][4] (32) ~= 130 VGPR ->
// 3-4 waves/SIMD. Merge: shfl_xor(8/16/32) with (val strict >, tie lower
// idx) == global first-max.
// Keep __launch_bounds__(256, 1): a (256,2) bound capped VGPR at 128 and
// spilled acc (111MB/dispatch scratch). DO NOT read rot via "uniform" global
// pointers (hipcc does not scalarize: 500us, R1). SINGLE loop nest, no
// fallback branch (old 2-path variant: 6.8GB spill, 3.1ms).
__global__ __launch_bounds__(256, 1) void hash_kernel(const float* __restrict__ qk,
                                                      const float* __restrict__ rot,
                                                      int* __restrict__ bkt) {
  __shared__ float rotS[2 * 2048];  // [hh][f*32+i]
  int tid = threadIdx.x;
  int blk = blockIdx.x;  // (b*4 + hp)*16 + tile, grid = B*4*16 = 1024
  int tile = blk & 15;
  int bhp = blk >> 4;
  int hp = bhp & 3, b = bhp >> 2;

  for (int i = tid; i < 4096; i += 256) {
    int hh = i >> 11, r = i & 2047;
    int f = r >> 5, ii = r & 31;
    rotS[i] = rot[(((size_t)b * 64 + f) * 8 + (hp * 2 + hh)) * 32 + ii];
  }
  __syncthreads();

  int lane = tid & 63, w = tid >> 6;
  int s = lane & 7, gi = lane >> 3;
  int t0 = (tile << 8) + (w << 6) + (s << 3);  // thread tokens: t0+k, k=0..7
  const float* qb = qk + (((size_t)b << 12) << 6);

  float2v accA[8][2], accB[8][2];  // [token][bucket-pair], rounds A/B
#pragma unroll
  for (int k = 0; k < 8; k++) {
    accA[k][0] = (float2v){0.f, 0.f};
    accA[k][1] = (float2v){0.f, 0.f};
    accB[k][0] = (float2v){0.f, 0.f};
    accB[k][1] = (float2v){0.f, 0.f};
  }

#pragma unroll 1
  for (int fq = 0; fq < 16; fq++) {
    float q4[8][4];
#pragma unroll
    for (int k = 0; k < 8; k++)
      *(float4*)(q4[k]) =
          *(const float4*)(qb + ((size_t)(t0 + k) << 6) + fq * 4);
#pragma unroll
    for (int fi = 0; fi < 4; fi++) {
      float4 wa = *(const float4*)(rotS + (fq * 4 + fi) * 32 + gi * 4);
      float4 wb = *(const float4*)(rotS + 2048 + (fq * 4 + fi) * 32 + gi * 4);
      float2v wa0 = {wa.x, wa.y}, wa1 = {wa.z, wa.w};
      float2v wb0 = {wb.x, wb.y}, wb1 = {wb.z, wb.w};
#pragma unroll
      for (int k = 0; k < 8; k++) {
        float2v q2 = {q4[k][fi], q4[k][fi]};
        float2v p0, p1, p2, p3;
        asm("v_pk_mul_f32 %0, %2, %3\n\t"
            "v_pk_add_f32 %1, %1, %0"
            : "=&v"(p0), "+v"(accA[k][0])
            : "v"(q2), "v"(wa0));
        asm("v_pk_mul_f32 %0, %2, %3\n\t"
            "v_pk_add_f32 %1, %1, %0"
            : "=&v"(p1), "+v"(accA[k][1])
            : "v"(q2), "v"(wa1));
        asm("v_pk_mul_f32 %0, %2, %3\n\t"
            "v_pk_add_f32 %1, %1, %0"
            : "=&v"(p2), "+v"(accB[k][0])
            : "v"(q2), "v"(wb0));
        asm("v_pk_mul_f32 %0, %2, %3\n\t"
            "v_pk_add_f32 %1, %1, %0"
            : "=&v"(p3), "+v"(accB[k][1])
            : "v"(q2), "v"(wb1));
      }
    }
  }

  int gb4 = gi * 4;
  size_t baseA = ((size_t)(b * 8 + hp * 2)) << 12;
  size_t baseB = ((size_t)(b * 8 + hp * 2 + 1)) << 12;
#pragma unroll
  for (int k = 0; k < 8; k++) {
    {
      float a[4] = {accA[k][0].x, accA[k][0].y, accA[k][1].x, accA[k][1].y};
      float bv = a[0];
      int bi = gb4;
#pragma unroll
      for (int j = 1; j < 4; j++)
        if (a[j] > bv) { bv = a[j]; bi = gb4 + j; }
#pragma unroll
      for (int j = 0; j < 4; j++) {
        float x = -a[j];
        if (x > bv) { bv = x; bi = 32 + gb4 + j; }
      }
#pragma unroll
      for (int off = 8; off < 64; off <<= 1) {
        float ov = __shfl_xor(bv, off);
        int oi = __shfl_xor(bi, off);
        if (ov > bv || (ov == bv && oi < bi)) { bv = ov; bi = oi; }
      }
      if (gi == 0) bkt[baseA + t0 + k] = bi;
    }
    {
      float a[4] = {accB[k][0].x, accB[k][0].y, accB[k][1].x, accB[k][1].y};
      float bv = a[0];
      int bi = gb4;
#pragma unroll
      for (int j = 1; j < 4; j++)
        if (a[j] > bv) { bv = a[j]; bi = gb4 + j; }
#pragma unroll
      for (int j = 0; j < 4; j++) {
        float x = -a[j];
        if (x > bv) { bv = x; bi = 32 + gb4 + j; }
      }
#pragma unroll
      for (int off = 8; off < 64; off <<= 1) {
        float ov = __shfl_xor(bv, off);
        int oi = __shfl_xor(bi, off);
        if (ov > bv || (ov == bv && oi < bi)) { bv = ov; bi = oi; }
      }
      if (gi == 0) bkt[baseB + t0 + k] = bi;
    }
  }
}

// ---------------- Kernel 2: stable counting sort per (b,h) ----------------
// v2: 1024 threads/block (neutral vs 256, kept).
__global__ __launch_bounds__(1024) void sort_kernel(const int* __restrict__ bkt,
                                                    int* __restrict__ st) {
  __shared__ int lb[4096];
  __shared__ int hist[4096];  // [chunk(64)][bucket(64)]
  __shared__ int cumoff[64];
  int tid = threadIdx.x;
  int b = blockIdx.x >> 3, h = blockIdx.x & 7;
  const int* gb = bkt + (((size_t)(b * 8 + h)) << 12);
  for (int t = tid; t < 4096; t += 1024) lb[t] = gb[t];
  for (int i = tid; i < 4096; i += 1024) hist[i] = 0;
  __syncthreads();
  for (int t = tid; t < 4096; t += 1024) atomicAdd(&hist[((t >> 6) << 6) | lb[t]], 1);
  __syncthreads();
  if (tid < 64) {
    int run = 0;
    for (int cc = 0; cc < 64; cc++) {
      int x = hist[(cc << 6) | tid];
      hist[(cc << 6) | tid] = run;
      run += x;
    }
    // exclusive prefix over buckets via wave-0 shfl scan
    int s = run;
    for (int off = 1; off < 64; off <<= 1) {
      int u = __shfl_up(s, off);
      if (tid >= off) s += u;
    }
    cumoff[tid] = s - run;
  }
  __syncthreads();
  int lane = tid & 63;
  for (int p = 0; p < 4; p++) {
    int t = (p << 10) + tid;  // each wave covers one aligned 64-token chunk
    int vb = lb[t];
    unsigned long long m = 0xFFFFFFFFFFFFFFFFull;
#pragma unroll
    for (int bit = 0; bit < 6; bit++) {
      unsigned long long bl = __ballot((vb >> bit) & 1);
      m &= ((vb >> bit) & 1) ? bl : ~bl;
    }
    int rank = __popcll(m & ((1ull << lane) - 1ull));
    int cpos = cumoff[vb] + hist[((t >> 6) << 6) | vb] + rank;
    st[(((size_t)(b * 8 + h)) << 12) + cpos] = t;
  }
}

// ---------------- Kernel 3: fused chunk kernel ----------------
// Per (b, round, chunk): QK^T (MFMA) -> per-round softmax -> P.V (MFMA),
// write normalized per-round output o_r (fp16) + lse_r. No atomics.
// grid: B*512 blocks, 256 threads = 4 waves. Measured 70.9us (R10).
// v6: XCD-aware block mapping (T1): b in low 4 bits -> XCD = b&7 -> per-XCD
// 2-batch L2 tile (2.1MB fits 4MB L2). CONFIRMED on counters: FETCH 62->11MB.
// Time only -2us -> gathers were not the critical path; this kernel has
// resisted 5 orthogonal probes (VALU cut, occupancy, direct stores, barrier
// cuts, L2 fix) at ~71-74us. Do not churn without a new counter signal.
// R6's direct-2B-store epilogue REGRESSED (74->81): keep O->LDS->b128.
// v3: structural self-mask (st is a permutation: current-chunk self-match is
// key_idx==row_idx, nt==w uniform; look-back needs token compares only for
// the 8 c==0 chunks); exp2-domain softmax (MASK2 = -50000*log2e).
// v2: single-exp softmax, both V halves staged up front; the P-write ->
// pfr-read hop is intra-wave only (wave w writes/reads P rows [16w,16w+16)),
// no barrier there.
#define MASK2 -72134.76f
__global__ __launch_bounds__(256) void chunk_kernel(const half_t* __restrict__ khat,
                                                    const half_t* __restrict__ vh,
                                                    const float* __restrict__ norm,
                                                    const int* __restrict__ st,
                                                    half_t* __restrict__ oh,
                                                    float* __restrict__ lse) {
  __shared__ __align__(16) half_t Ks[128 * KSTR];  // K; later P (64 rows, PSTR)
  __shared__ __align__(16) half_t Vt0[64 * VSTR];  // V^T keys 0..63; later O
  __shared__ __align__(16) half_t Vt1[64 * VSTR];  // V^T keys 64..127
  __shared__ int tk[128];
  __shared__ float normS[64];
  int tid = threadIdx.x;
  // XCD swizzle: b in low 4 bits -> XCD = b & 7 -> per-XCD 2-batch L2 tile
  int b = blockIdx.x & 15;
  int g = blockIdx.x >> 4;
  int h = g >> 6, c = g & 63;
  int gp = (g + 511) & 511;
  int hp = gp >> 6, cp = gp & 63;
  if (tid < 64) {
    tk[tid] = st[(((size_t)(b * 8 + h)) << 12) + (c << 6) + tid];
  } else if (tid < 128) {
    tk[tid] = st[(((size_t)(b * 8 + hp)) << 12) + (cp << 6) + (tid - 64)];
  }
  __syncthreads();
  if (tid < 64) normS[tid] = norm[(b << 12) + tk[tid]];
  // stage K (128 rows): single b128 load -> single b128 LDS store
  for (int idx = tid; idx < 1024; idx += 256) {
    int row = idx >> 3, fo = idx & 7;
    half8 val = *(const half8*)(khat + (((size_t)(b << 12) + tk[row]) << 6) + fo * 8);
    *(half8*)(Ks + row * KSTR + fo * 8) = val;
  }
  // stage BOTH V halves transposed (all gathers in flight together)
  {
    int kp = tid & 31, ch = tid >> 5;  // ch in 0..7
    half8 r0 = *(const half8*)(vh + (((size_t)(b << 12) + tk[2 * kp]) << 6) + ch * 8);
    half8 r1 = *(const half8*)(vh + (((size_t)(b << 12) + tk[2 * kp + 1]) << 6) + ch * 8);
    half8 r2 = *(const half8*)(vh + (((size_t)(b << 12) + tk[64 + 2 * kp]) << 6) + ch * 8);
    half8 r3 = *(const half8*)(vh + (((size_t)(b << 12) + tk[65 + 2 * kp]) << 6) + ch * 8);
#pragma unroll
    for (int j = 0; j < 8; j++) {
      half2t p0 = {r0[j], r1[j]};
      half2t p1 = {r2[j], r3[j]};
      *(half2t*)(Vt0 + (ch * 8 + j) * VSTR + 2 * kp) = p0;
      *(half2t*)(Vt1 + (ch * 8 + j) * VSTR + 2 * kp) = p1;
    }
  }
  __syncthreads();

  int lane = tid & 63, w = tid >> 6;
  int m = lane & 15, quad = lane >> 4;
  half8 afr[2];
#pragma unroll
  for (int ki = 0; ki < 2; ki++)
    afr[ki] = *(const half8*)(Ks + (w * 16 + m) * KSTR + ki * 32 + quad * 8);
  bool c0 = (c == 0);
  float scr[4];
#pragma unroll
  for (int r = 0; r < 4; r++) {
    int rr = w * 16 + quad * 4 + r;
    scr[r] = 0.18033688f * normS[rr];  // 0.125 * log2(e)
  }
  int ti[4] = {0, 0, 0, 0};
  if (c0) {
#pragma unroll
    for (int r = 0; r < 4; r++) ti[r] = tk[w * 16 + quad * 4 + r];
  }

  // QK^T dots (log2 domain), masked + scaled
  float d[8][4];
#pragma unroll
  for (int nt = 0; nt < 8; nt++) {
    floatx4 acc = {0.f, 0.f, 0.f, 0.f};
#pragma unroll
    for (int ki = 0; ki < 2; ki++) {
      half8 bfr = *(const half8*)(Ks + (nt * 16 + m) * KSTR + ki * 32 + quad * 8);
      acc = __builtin_amdgcn_mfma_f32_16x16x32_f16(afr[ki], bfr, acc, 0, 0, 0);
    }
    if (nt < 4) {
      // current-chunk keys: self-match iff key_idx == row_idx (permutation)
      if (nt == w) {
#pragma unroll
        for (int r = 0; r < 4; r++)
          d[nt][r] = (m == quad * 4 + r) ? MASK2 : acc[r] * scr[r];
      } else {
#pragma unroll
        for (int r = 0; r < 4; r++) d[nt][r] = acc[r] * scr[r];
      }
    } else {
      // look-back keys: same-round prev chunk (c>0) has distinct tokens
      if (c0) {
        int tj = tk[nt * 16 + m];
#pragma unroll
        for (int r = 0; r < 4; r++)
          d[nt][r] = (ti[r] == tj) ? MASK2 : acc[r] * scr[r];
      } else {
#pragma unroll
        for (int r = 0; r < 4; r++) d[nt][r] = acc[r] * scr[r];
      }
    }
  }

  // per-round row softmax (log2 domain): max, exp2 once in place, sum
  float mr4[4], lr4[4];
#pragma unroll
  for (int r = 0; r < 4; r++) {
    float mm = d[0][r];
#pragma unroll
    for (int nt = 1; nt < 8; nt++) mm = fmaxf(mm, d[nt][r]);
    for (int off = 1; off < 16; off <<= 1) mm = fmaxf(mm, __shfl_xor(mm, off));
    mr4[r] = mm;
  }
#pragma unroll
  for (int nt = 0; nt < 8; nt++)
#pragma unroll
    for (int r = 0; r < 4; r++)
      d[nt][r] = __builtin_amdgcn_exp2f(d[nt][r] - mr4[r]);
#pragma unroll
  for (int r = 0; r < 4; r++) {
    float ll = 0.f;
#pragma unroll
    for (int nt = 0; nt < 8; nt++) ll += d[nt][r];
    for (int off = 1; off < 16; off <<= 1) ll += __shfl_xor(ll, off);
    lr4[r] = ll;
    if (m == 0) {
      int rr = w * 16 + quad * 4 + r;
      lse[(((size_t)(b * 8 + h)) << 12) + tk[rr]] =
          0.69314718f * (mr4[r] + __builtin_amdgcn_logf(ll));
    }
  }
  __syncthreads();  // all waves done reading Ks as K

  // P' = exp2(d - m_r) fp16 into Ks region (stride PSTR); values already in d
  half_t* Ps = Ks;
#pragma unroll
  for (int nt = 0; nt < 8; nt++) {
#pragma unroll
    for (int r = 0; r < 4; r++) {
      Ps[(w * 16 + quad * 4 + r) * PSTR + nt * 16 + m] = (half_t)d[nt][r];
    }
  }
  // intra-wave RAW only (own 16 rows) -> compiler-ordered via lgkmcnt, no barrier

  half8 pfr[4];
#pragma unroll
  for (int kk = 0; kk < 4; kk++)
    pfr[kk] = *(const half8*)(Ps + (w * 16 + m) * PSTR + kk * 32 + quad * 8);

  floatx4 accO[4];
#pragma unroll
  for (int dt = 0; dt < 4; dt++) accO[dt] = (floatx4){0.f, 0.f, 0.f, 0.f};

  // PV over all 128 keys, contiguous MFMA cluster
#pragma unroll
  for (int dt = 0; dt < 4; dt++) {
#pragma unroll
    for (int kk = 0; kk < 2; kk++) {
      half8 bfr = *(const half8*)(Vt0 + (dt * 16 + m) * VSTR + kk * 32 + quad * 8);
      accO[dt] = __builtin_amdgcn_mfma_f32_16x16x32_f16(pfr[kk], bfr, accO[dt], 0, 0, 0);
    }
#pragma unroll
    for (int kk = 2; kk < 4; kk++) {
      half8 bfr = *(const half8*)(Vt1 + (dt * 16 + m) * VSTR + (kk - 2) * 32 + quad * 8);
      accO[dt] = __builtin_amdgcn_mfma_f32_16x16x32_f16(pfr[kk], bfr, accO[dt], 0, 0, 0);
    }
  }
  __syncthreads();  // all Vt0 reads done; reuse Vt0 for O

  // normalized O (fp16) -> LDS, then coalesced 16B row stores
  half_t* Ot = Vt0;
#pragma unroll
  for (int r = 0; r < 4; r++) {
    float inv = 1.0f / lr4[r];
#pragma unroll
    for (int dt = 0; dt < 4; dt++) {
      Ot[(w * 16 + quad * 4 + r) * VSTR + dt * 16 + m] = (half_t)(accO[dt][r] * inv);
    }
  }
  __syncthreads();
  for (int idx = tid; idx < 512; idx += 256) {
    int row = idx >> 3, fo = idx & 7;
    half8 val = *(const half8*)(Ot + row * VSTR + fo * 8);
    *(half8*)(oh + ((((size_t)(b * 8 + h)) << 12) + tk[row]) * 64 + fo * 8) = val;
  }
}

// ---------------- Kernel 4: combine rounds ----------------
// out[b,t,:] = sum_r exp(lse_r - lse_tot) * o_r[b,t,:]
// grid: B*S*8/256 blocks; thread = (token, 8-dim group)
__global__ __launch_bounds__(256) void combine_kernel(const half_t* __restrict__ oh,
                                                      const float* __restrict__ lse,
                                                      float* __restrict__ out) {
  int idx = blockIdx.x * 256 + threadIdx.x;  // over B*S*8
  int do8 = idx & 7;
  int ts = idx >> 3;  // b*4096 + t
  int b = ts >> 12, t = ts & 4095;
  size_t base = ((size_t)b << 15) + t;  // (b*8)<<12 + t
  float L[8];
  float m = -3.4e38f;
#pragma unroll
  for (int h = 0; h < 8; h++) {
    L[h] = lse[base + ((size_t)h << 12)];
    m = fmaxf(m, L[h]);
  }
  float s = 0.f;
#pragma unroll
  for (int h = 0; h < 8; h++) s += __expf(L[h] - m);
  float lt = m + __logf(s);
  float acc[8];
#pragma unroll
  for (int j = 0; j < 8; j++) acc[j] = 0.f;
#pragma unroll
  for (int h = 0; h < 8; h++) {
    float wgt = __expf(L[h] - lt);
    half8 o = *(const half8*)(oh + ((base + ((size_t)h << 12)) << 6) + do8 * 8);
#pragma unroll
    for (int j = 0; j < 8; j++) acc[j] += wgt * (float)o[j];
  }
  float* dst = out + ((((size_t)b << 12) + t) << 6) + do8 * 8;
  *(float4*)dst = (float4){acc[0], acc[1], acc[2], acc[3]};
  *(float4*)(dst + 4) = (float4){acc[4], acc[5], acc[6], acc[7]};
}

extern "C" void kernel_launch(void* const* d_in, const int* in_sizes, int n_in,
                              void* d_out, int out_size, void* d_ws, size_t ws_size,
                              hipStream_t stream) {
  const float* qk = (const float*)d_in[0];
  const float* v = (const float*)d_in[1];
  const float* rot = (const float*)d_in[2];
  float* out = (float*)d_out;

  int* bkt = (int*)d_ws;                            // 2MB
  int* stp = bkt + NB_B * NB_H * NB_S;              // 2MB
  float* lse = (float*)(stp + NB_B * NB_H * NB_S);  // 2MB
  float* norm = lse + NB_B * NB_H * NB_S;           // 256KB
  half_t* khat = (half_t*)(norm + NB_B * NB_S);     // 8MB
  half_t* vh = khat + (size_t)NB_B * NB_S * NB_D;   // 8MB
  half_t* oh = vh + (size_t)NB_B * NB_S * NB_D;     // B*H*S*D fp16 = 67MB

  prep_kernel<<<NB_B * NB_S * 16 / 256, 256, 0, stream>>>(qk, v, khat, vh, norm);
  hash_kernel<<<NB_B * 4 * 16, 256, 0, stream>>>(qk, rot, bkt);
  sort_kernel<<<NB_B * NB_H, 1024, 0, stream>>>(bkt, stp);
  chunk_kernel<<<NB_B * 512, 256, 0, stream>>>(khat, vh, norm, stp, oh, lse);
  combine_kernel<<<NB_B * NB_S * 8 / 256, 256, 0, stream>>>(oh, lse, out);
}

// Round 12
// 225.844 us; speedup vs baseline: 1.0328x; 1.0328x over previous
//
#include <hip/hip_runtime.h>
#include <math.h>

#define NB_B 16
#define NB_S 4096
#define NB_D 64
#define NB_H 8

// LDS strides (in halfs) chosen so rows are 16B-aligned: 72*2=144=16*9,
// 136*2=272=16*17 -> every MFMA fragment is a single ds_read_b128.
#define KSTR 72
#define PSTR 136
#define VSTR 72

typedef _Float16 half_t;
typedef __attribute__((ext_vector_type(2))) _Float16 half2t;
typedef __attribute__((ext_vector_type(4))) _Float16 half4;
typedef __attribute__((ext_vector_type(8))) _Float16 half8;
typedef __attribute__((ext_vector_type(4))) float floatx4;
typedef __attribute__((ext_vector_type(2))) float float2v;

// ---------------- Kernel 0+1 FUSED: prep + LSH hashing ----------------
// prep and hash are INDEPENDENT (prep: qk,v -> khat,vh,norm; hash: qk,rot ->
// bkt); R0-R10 ran them serially, paying ~10us prep + a launch gap. Fused as
// a block-range branch: blocks 0..511 run hash v9 VERBATIM (R10's best:
// rounds-interleaved 2-tok pk, total 204.6us), blocks 512..4607 run prep
// VERBATIM. Branch is blockIdx-uniform; hash dominates VGPR so its codegen
// is unchanged; prep blocks are brief and memory-bound -> they fill CU slots
// around the VALU-bound hash blocks.
// R11 post-mortem (cooperative bucket split): REGRESSED 204.6->233.3
// (8x-redundant q-loads + addressing VALU: 83.5us, VALUBusy 46%). Reverted.
// Hash lane history: 1/2/4-tok, scalar/pk, rounds outer/interleaved, coop
// split -- best is THIS v9 (hash <= 70.6us, never in R10 top-5).
// Keep __launch_bounds__(256, 1): a (256,2) bound capped VGPR at 128 and
// spilled acc (111MB/dispatch scratch). DO NOT read rot via "uniform" global
// pointers (hipcc does not scalarize: 500us, R1). SINGLE loop nest, no
// fallback branch (old 2-path variant: 6.8GB spill, 3.1ms).
__global__ __launch_bounds__(256, 1) void hashprep_kernel(
    const float* __restrict__ qk, const float* __restrict__ v,
    const float* __restrict__ rot, int* __restrict__ bkt,
    half_t* __restrict__ khat, half_t* __restrict__ vh,
    float* __restrict__ norm) {
  __shared__ float rotS[2 * 2048];  // [hh][f*32+i] (hash path only)
  int tid = threadIdx.x;

  if (blockIdx.x >= 512) {
    // ---------------- prep path (4096 blocks) ----------------
    int g = (blockIdx.x - 512) * 256 + tid;  // over B*S*16
    float4 qv = ((const float4*)qk)[g];
    float4 vv = ((const float4*)v)[g];
    float ss = qv.x * qv.x + qv.y * qv.y + qv.z * qv.z + qv.w * qv.w;
    for (int off = 1; off < 16; off <<= 1) ss += __shfl_xor(ss, off);
    float nr = fmaxf(sqrtf(ss), 1e-12f);
    float sc = 1.0f / nr;
    half4 hk = {(half_t)(qv.x * sc), (half_t)(qv.y * sc), (half_t)(qv.z * sc),
                (half_t)(qv.w * sc)};
    half4 hv = {(half_t)vv.x, (half_t)vv.y, (half_t)vv.z, (half_t)vv.w};
    ((half4*)khat)[g] = hk;
    ((half4*)vh)[g] = hv;
    if ((tid & 15) == 0) norm[g >> 4] = nr;
    return;
  }

  // ---------------- hash path (512 blocks), v9 verbatim ----------------
  int blk = blockIdx.x;  // (b*4 + hp)*8 + tile
  int tile = blk & 7;
  int bhp = blk >> 3;
  int hp = bhp & 3, b = bhp >> 2;

  for (int i = tid; i < 4096; i += 256) {
    int hh = i >> 11, r = i & 2047;
    int f = r >> 5, ii = r & 31;
    rotS[i] = rot[(((size_t)b * 64 + f) * 8 + (hp * 2 + hh)) * 32 + ii];
  }
  __syncthreads();

  int t0 = (tile << 9) + tid;  // thread's tokens: t0 + 256*tok, tok=0..1
  const float* qb = qk + (((size_t)b << 12) << 6);

  float2v accA[2][16];  // round hh=0: 16 pairs = 32 buckets per token
  float2v accB[2][16];  // round hh=1
#pragma unroll
  for (int tok = 0; tok < 2; tok++)
#pragma unroll
    for (int i = 0; i < 16; i++) {
      accA[tok][i] = (float2v){0.f, 0.f};
      accB[tok][i] = (float2v){0.f, 0.f};
    }

#pragma unroll 1
  for (int fc = 0; fc < 8; fc++) {
    float q[2][8];
#pragma unroll
    for (int tok = 0; tok < 2; tok++) {
      const float4* qr =
          (const float4*)(qb + ((size_t)(t0 + (tok << 8)) << 6) + fc * 8);
      *(float4*)(q[tok]) = qr[0];
      *(float4*)(q[tok] + 4) = qr[1];
    }
#pragma unroll
    for (int fi = 0; fi < 8; fi++) {
#pragma unroll
      for (int i4 = 0; i4 < 8; i4++) {
        float4 wa = *(const float4*)(rotS + (fc * 8 + fi) * 32 + i4 * 4);
        float4 wb = *(const float4*)(rotS + 2048 + (fc * 8 + fi) * 32 + i4 * 4);
        float2v wa0 = {wa.x, wa.y}, wa1 = {wa.z, wa.w};
        float2v wb0 = {wb.x, wb.y}, wb1 = {wb.z, wb.w};
#pragma unroll
        for (int tok = 0; tok < 2; tok++) {
          float2v q2 = {q[tok][fi], q[tok][fi]};
          float2v p0, p1, p2, p3;
          asm("v_pk_mul_f32 %0, %2, %3\n\t"
              "v_pk_add_f32 %1, %1, %0"
              : "=&v"(p0), "+v"(accA[tok][i4 * 2])
              : "v"(q2), "v"(wa0));
          asm("v_pk_mul_f32 %0, %2, %3\n\t"
              "v_pk_add_f32 %1, %1, %0"
              : "=&v"(p1), "+v"(accA[tok][i4 * 2 + 1])
              : "v"(q2), "v"(wa1));
          asm("v_pk_mul_f32 %0, %2, %3\n\t"
              "v_pk_add_f32 %1, %1, %0"
              : "=&v"(p2), "+v"(accB[tok][i4 * 2])
              : "v"(q2), "v"(wb0));
          asm("v_pk_mul_f32 %0, %2, %3\n\t"
              "v_pk_add_f32 %1, %1, %0"
              : "=&v"(p3), "+v"(accB[tok][i4 * 2 + 1])
              : "v"(q2), "v"(wb1));
        }
      }
    }
  }

#define HASH_ARGMAX(ACC, H)                                              \
  {                                                                      \
    int h = (H);                                                         \
    _Pragma("unroll") for (int tok = 0; tok < 2; tok++) {                \
      float a[32];                                                       \
      _Pragma("unroll") for (int p = 0; p < 16; p++) {                   \
        a[2 * p] = ACC[tok][p].x;                                        \
        a[2 * p + 1] = ACC[tok][p].y;                                    \
      }                                                                  \
      float b1 = a[0];                                                   \
      int i1 = 0;                                                        \
      _Pragma("unroll") for (int i = 1; i < 32; i++) if (a[i] > b1) {    \
        b1 = a[i];                                                       \
        i1 = i;                                                          \
      }                                                                  \
      _Pragma("unroll") for (int i = 0; i < 32; i++) {                   \
        float x = -a[i];                                                 \
        if (x > b1) {                                                    \
          b1 = x;                                                        \
          i1 = 32 + i;                                                   \
        }                                                                \
      }                                                                  \
      bkt[(((size_t)(b * 8 + h)) << 12) + t0 + (tok << 8)] = i1;         \
    }                                                                    \
  }

  HASH_ARGMAX(accA, hp * 2)
  HASH_ARGMAX(accB, hp * 2 + 1)
#undef HASH_ARGMAX
}

// ---------------- Kernel 2: stable counting sort per (b,h) ----------------
// v2: 1024 threads/block (neutral vs 256, kept).
__global__ __launch_bounds__(1024) void sort_kernel(const int* __restrict__ bkt,
                                                    int* __restrict__ st) {
  __shared__ int lb[4096];
  __shared__ int hist[4096];  // [chunk(64)][bucket(64)]
  __shared__ int cumoff[64];
  int tid = threadIdx.x;
  int b = blockIdx.x >> 3, h = blockIdx.x & 7;
  const int* gb = bkt + (((size_t)(b * 8 + h)) << 12);
  for (int t = tid; t < 4096; t += 1024) lb[t] = gb[t];
  for (int i = tid; i < 4096; i += 1024) hist[i] = 0;
  __syncthreads();
  for (int t = tid; t < 4096; t += 1024) atomicAdd(&hist[((t >> 6) << 6) | lb[t]], 1);
  __syncthreads();
  if (tid < 64) {
    int run = 0;
    for (int cc = 0; cc < 64; cc++) {
      int x = hist[(cc << 6) | tid];
      hist[(cc << 6) | tid] = run;
      run += x;
    }
    // exclusive prefix over buckets via wave-0 shfl scan
    int s = run;
    for (int off = 1; off < 64; off <<= 1) {
      int u = __shfl_up(s, off);
      if (tid >= off) s += u;
    }
    cumoff[tid] = s - run;
  }
  __syncthreads();
  int lane = tid & 63;
  for (int p = 0; p < 4; p++) {
    int t = (p << 10) + tid;  // each wave covers one aligned 64-token chunk
    int vb = lb[t];
    unsigned long long m = 0xFFFFFFFFFFFFFFFFull;
#pragma unroll
    for (int bit = 0; bit < 6; bit++) {
      unsigned long long bl = __ballot((vb >> bit) & 1);
      m &= ((vb >> bit) & 1) ? bl : ~bl;
    }
    int rank = __popcll(m & ((1ull << lane) - 1ull));
    int cpos = cumoff[vb] + hist[((t >> 6) << 6) | vb] + rank;
    st[(((size_t)(b * 8 + h)) << 12) + cpos] = t;
  }
}

// ---------------- Kernel 3: fused chunk kernel ----------------
// Per (b, round, chunk): QK^T (MFMA) -> per-round softmax -> P.V (MFMA),
// write normalized per-round output o_r (fp16) + lse_r. No atomics.
// grid: B*512 blocks, 256 threads = 4 waves. Measured 70.9us (R10).
// v6: XCD-aware block mapping (T1): b in low 4 bits -> XCD = b&7 -> per-XCD
// 2-batch L2 tile (2.1MB fits 4MB L2). CONFIRMED on counters: FETCH 62->11MB.
// Time only -2us -> gathers were not the critical path; this kernel has
// resisted 5 orthogonal probes (VALU cut, occupancy, direct stores, barrier
// cuts, L2 fix) at ~71-74us. Do not churn without a new counter signal.
// R6's direct-2B-store epilogue REGRESSED (74->81): keep O->LDS->b128.
// v3: structural self-mask (st is a permutation: current-chunk self-match is
// key_idx==row_idx, nt==w uniform; look-back needs token compares only for
// the 8 c==0 chunks); exp2-domain softmax (MASK2 = -50000*log2e).
// v2: single-exp softmax, both V halves staged up front; the P-write ->
// pfr-read hop is intra-wave only (wave w writes/reads P rows [16w,16w+16)),
// no barrier there.
#define MASK2 -72134.76f
__global__ __launch_bounds__(256) void chunk_kernel(const half_t* __restrict__ khat,
                                                    const half_t* __restrict__ vh,
                                                    const float* __restrict__ norm,
                                                    const int* __restrict__ st,
                                                    half_t* __restrict__ oh,
                                                    float* __restrict__ lse) {
  __shared__ __align__(16) half_t Ks[128 * KSTR];  // K; later P (64 rows, PSTR)
  __shared__ __align__(16) half_t Vt0[64 * VSTR];  // V^T keys 0..63; later O
  __shared__ __align__(16) half_t Vt1[64 * VSTR];  // V^T keys 64..127
  __shared__ int tk[128];
  __shared__ float normS[64];
  int tid = threadIdx.x;
  // XCD swizzle: b in low 4 bits -> XCD = b & 7 -> per-XCD 2-batch L2 tile
  int b = blockIdx.x & 15;
  int g = blockIdx.x >> 4;
  int h = g >> 6, c = g & 63;
  int gp = (g + 511) & 511;
  int hp = gp >> 6, cp = gp & 63;
  if (tid < 64) {
    tk[tid] = st[(((size_t)(b * 8 + h)) << 12) + (c << 6) + tid];
  } else if (tid < 128) {
    tk[tid] = st[(((size_t)(b * 8 + hp)) << 12) + (cp << 6) + (tid - 64)];
  }
  __syncthreads();
  if (tid < 64) normS[tid] = norm[(b << 12) + tk[tid]];
  // stage K (128 rows): single b128 load -> single b128 LDS store
  for (int idx = tid; idx < 1024; idx += 256) {
    int row = idx >> 3, fo = idx & 7;
    half8 val = *(const half8*)(khat + (((size_t)(b << 12) + tk[row]) << 6) + fo * 8);
    *(half8*)(Ks + row * KSTR + fo * 8) = val;
  }
  // stage BOTH V halves transposed (all gathers in flight together)
  {
    int kp = tid & 31, ch = tid >> 5;  // ch in 0..7
    half8 r0 = *(const half8*)(vh + (((size_t)(b << 12) + tk[2 * kp]) << 6) + ch * 8);
    half8 r1 = *(const half8*)(vh + (((size_t)(b << 12) + tk[2 * kp + 1]) << 6) + ch * 8);
    half8 r2 = *(const half8*)(vh + (((size_t)(b << 12) + tk[64 + 2 * kp]) << 6) + ch * 8);
    half8 r3 = *(const half8*)(vh + (((size_t)(b << 12) + tk[65 + 2 * kp]) << 6) + ch * 8);
#pragma unroll
    for (int j = 0; j < 8; j++) {
      half2t p0 = {r0[j], r1[j]};
      half2t p1 = {r2[j], r3[j]};
      *(half2t*)(Vt0 + (ch * 8 + j) * VSTR + 2 * kp) = p0;
      *(half2t*)(Vt1 + (ch * 8 + j) * VSTR + 2 * kp) = p1;
    }
  }
  __syncthreads();

  int lane = tid & 63, w = tid >> 6;
  int m = lane & 15, quad = lane >> 4;
  half8 afr[2];
#pragma unroll
  for (int ki = 0; ki < 2; ki++)
    afr[ki] = *(const half8*)(Ks + (w * 16 + m) * KSTR + ki * 32 + quad * 8);
  bool c0 = (c == 0);
  float scr[4];
#pragma unroll
  for (int r = 0; r < 4; r++) {
    int rr = w * 16 + quad * 4 + r;
    scr[r] = 0.18033688f * normS[rr];  // 0.125 * log2(e)
  }
  int ti[4] = {0, 0, 0, 0};
  if (c0) {
#pragma unroll
    for (int r = 0; r < 4; r++) ti[r] = tk[w * 16 + quad * 4 + r];
  }

  // QK^T dots (log2 domain), masked + scaled
  float d[8][4];
#pragma unroll
  for (int nt = 0; nt < 8; nt++) {
    floatx4 acc = {0.f, 0.f, 0.f, 0.f};
#pragma unroll
    for (int ki = 0; ki < 2; ki++) {
      half8 bfr = *(const half8*)(Ks + (nt * 16 + m) * KSTR + ki * 32 + quad * 8);
      acc = __builtin_amdgcn_mfma_f32_16x16x32_f16(afr[ki], bfr, acc, 0, 0, 0);
    }
    if (nt < 4) {
      // current-chunk keys: self-match iff key_idx == row_idx (permutation)
      if (nt == w) {
#pragma unroll
        for (int r = 0; r < 4; r++)
          d[nt][r] = (m == quad * 4 + r) ? MASK2 : acc[r] * scr[r];
      } else {
#pragma unroll
        for (int r = 0; r < 4; r++) d[nt][r] = acc[r] * scr[r];
      }
    } else {
      // look-back keys: same-round prev chunk (c>0) has distinct tokens
      if (c0) {
        int tj = tk[nt * 16 + m];
#pragma unroll
        for (int r = 0; r < 4; r++)
          d[nt][r] = (ti[r] == tj) ? MASK2 : acc[r] * scr[r];
      } else {
#pragma unroll
        for (int r = 0; r < 4; r++) d[nt][r] = acc[r] * scr[r];
      }
    }
  }

  // per-round row softmax (log2 domain): max, exp2 once in place, sum
  float mr4[4], lr4[4];
#pragma unroll
  for (int r = 0; r < 4; r++) {
    float mm = d[0][r];
#pragma unroll
    for (int nt = 1; nt < 8; nt++) mm = fmaxf(mm, d[nt][r]);
    for (int off = 1; off < 16; off <<= 1) mm = fmaxf(mm, __shfl_xor(mm, off));
    mr4[r] = mm;
  }
#pragma unroll
  for (int nt = 0; nt < 8; nt++)
#pragma unroll
    for (int r = 0; r < 4; r++)
      d[nt][r] = __builtin_amdgcn_exp2f(d[nt][r] - mr4[r]);
#pragma unroll
  for (int r = 0; r < 4; r++) {
    float ll = 0.f;
#pragma unroll
    for (int nt = 0; nt < 8; nt++) ll += d[nt][r];
    for (int off = 1; off < 16; off <<= 1) ll += __shfl_xor(ll, off);
    lr4[r] = ll;
    if (m == 0) {
      int rr = w * 16 + quad * 4 + r;
      lse[(((size_t)(b * 8 + h)) << 12) + tk[rr]] =
          0.69314718f * (mr4[r] + __builtin_amdgcn_logf(ll));
    }
  }
  __syncthreads();  // all waves done reading Ks as K

  // P' = exp2(d - m_r) fp16 into Ks region (stride PSTR); values already in d
  half_t* Ps = Ks;
#pragma unroll
  for (int nt = 0; nt < 8; nt++) {
#pragma unroll
    for (int r = 0; r < 4; r++) {
      Ps[(w * 16 + quad * 4 + r) * PSTR + nt * 16 + m] = (half_t)d[nt][r];
    }
  }
  // intra-wave RAW only (own 16 rows) -> compiler-ordered via lgkmcnt, no barrier

  half8 pfr[4];
#pragma unroll
  for (int kk = 0; kk < 4; kk++)
    pfr[kk] = *(const half8*)(Ps + (w * 16 + m) * PSTR + kk * 32 + quad * 8);

  floatx4 accO[4];
#pragma unroll
  for (int dt = 0; dt < 4; dt++) accO[dt] = (floatx4){0.f, 0.f, 0.f, 0.f};

  // PV over all 128 keys, contiguous MFMA cluster
#pragma unroll
  for (int dt = 0; dt < 4; dt++) {
#pragma unroll
    for (int kk = 0; kk < 2; kk++) {
      half8 bfr = *(const half8*)(Vt0 + (dt * 16 + m) * VSTR + kk * 32 + quad * 8);
      accO[dt] = __builtin_amdgcn_mfma_f32_16x16x32_f16(pfr[kk], bfr, accO[dt], 0, 0, 0);
    }
#pragma unroll
    for (int kk = 2; kk < 4; kk++) {
      half8 bfr = *(const half8*)(Vt1 + (dt * 16 + m) * VSTR + (kk - 2) * 32 + quad * 8);
      accO[dt] = __builtin_amdgcn_mfma_f32_16x16x32_f16(pfr[kk], bfr, accO[dt], 0, 0, 0);
    }
  }
  __syncthreads();  // all Vt0 reads done; reuse Vt0 for O

  // normalized O (fp16) -> LDS, then coalesced 16B row stores
  half_t* Ot = Vt0;
#pragma unroll
  for (int r = 0; r < 4; r++) {
    float inv = 1.0f / lr4[r];
#pragma unroll
    for (int dt = 0; dt < 4; dt++) {
      Ot[(w * 16 + quad * 4 + r) * VSTR + dt * 16 + m] = (half_t)(accO[dt][r] * inv);
    }
  }
  __syncthreads();
  for (int idx = tid; idx < 512; idx += 256) {
    int row = idx >> 3, fo = idx & 7;
    half8 val = *(const half8*)(Ot + row * VSTR + fo * 8);
    *(half8*)(oh + ((((size_t)(b * 8 + h)) << 12) + tk[row]) * 64 + fo * 8) = val;
  }
}

// ---------------- Kernel 4: combine rounds ----------------
// out[b,t,:] = sum_r exp(lse_r - lse_tot) * o_r[b,t,:]
// grid: B*S*8/256 blocks; thread = (token, 8-dim group)
__global__ __launch_bounds__(256) void combine_kernel(const half_t* __restrict__ oh,
                                                      const float* __restrict__ lse,
                                                      float* __restrict__ out) {
  int idx = blockIdx.x * 256 + threadIdx.x;  // over B*S*8
  int do8 = idx & 7;
  int ts = idx >> 3;  // b*4096 + t
  int b = ts >> 12, t = ts & 4095;
  size_t base = ((size_t)b << 15) + t;  // (b*8)<<12 + t
  float L[8];
  float m = -3.4e38f;
#pragma unroll
  for (int h = 0; h < 8; h++) {
    L[h] = lse[base + ((size_t)h << 12)];
    m = fmaxf(m, L[h]);
  }
  float s = 0.f;
#pragma unroll
  for (int h = 0; h < 8; h++) s += __expf(L[h] - m);
  float lt = m + __logf(s);
  float acc[8];
#pragma unroll
  for (int j = 0; j < 8; j++) acc[j] = 0.f;
#pragma unroll
  for (int h = 0; h < 8; h++) {
    float wgt = __expf(L[h] - lt);
    half8 o = *(const half8*)(oh + ((base + ((size_t)h << 12)) << 6) + do8 * 8);
#pragma unroll
    for (int j = 0; j < 8; j++) acc[j] += wgt * (float)o[j];
  }
  float* dst = out + ((((size_t)b << 12) + t) << 6) + do8 * 8;
  *(float4*)dst = (float4){acc[0], acc[1], acc[2], acc[3]};
  *(float4*)(dst + 4) = (float4){acc[4], acc[5], acc[6], acc[7]};
}

extern "C" void kernel_launch(void* const* d_in, const int* in_sizes, int n_in,
                              void* d_out, int out_size, void* d_ws, size_t ws_size,
                              hipStream_t stream) {
  const float* qk = (const float*)d_in[0];
  const float* v = (const float*)d_in[1];
  const float* rot = (const float*)d_in[2];
  float* out = (float*)d_out;

  int* bkt = (int*)d_ws;                            // 2MB
  int* stp = bkt + NB_B * NB_H * NB_S;              // 2MB
  float* lse = (float*)(stp + NB_B * NB_H * NB_S);  // 2MB
  float* norm = lse + NB_B * NB_H * NB_S;           // 256KB
  half_t* khat = (half_t*)(norm + NB_B * NB_S);     // 8MB
  half_t* vh = khat + (size_t)NB_B * NB_S * NB_D;   // 8MB
  half_t* oh = vh + (size_t)NB_B * NB_S * NB_D;     // B*H*S*D fp16 = 67MB

  // fused prep+hash: blocks 0..511 hash, 512..4607 prep (independent ops)
  hashprep_kernel<<<512 + NB_B * NB_S * 16 / 256, 256, 0, stream>>>(
      qk, v, rot, bkt, khat, vh, norm);
  sort_kernel<<<NB_B * NB_H, 1024, 0, stream>>>(bkt, stp);
  chunk_kernel<<<NB_B * 512, 256, 0, stream>>>(khat, vh, norm, stp, oh, lse);
  combine_kernel<<<NB_B * NB_S * 8 / 256, 256, 0, stream>>>(oh, lse, out);
}

// Round 13
// 205.952 us; speedup vs baseline: 1.1326x; 1.0966x over previous
//
#include <hip/hip_runtime.h>
#include <math.h>

#define NB_B 16
#define NB_S 4096
#define NB_D 64
#define NB_H 8

// LDS strides (in halfs) chosen so rows are 16B-aligned: 72*2=144=16*9,
// 136*2=272=16*17 -> every MFMA fragment is a single ds_read_b128.
#define KSTR 72
#define PSTR 136
#define VSTR 72

typedef _Float16 half_t;
typedef __attribute__((ext_vector_type(2))) _Float16 half2t;
typedef __attribute__((ext_vector_type(4))) _Float16 half4;
typedef __attribute__((ext_vector_type(8))) _Float16 half8;
typedef __attribute__((ext_vector_type(4))) float floatx4;
typedef __attribute__((ext_vector_type(2))) float float2v;

// ---------------- Kernel 0: precompute fp16 k-hat, v, f32 norm ----------------
// grid: B*S*16/256 blocks; 16 lanes per row. q = norm * khat (Q never stored).
// R12 post-mortem: fusing prep into hash REGRESSED (204.6 -> 225.8): the
// fused kernel's 132-VGPR/16KB-LDS allocation throttled prep's memory-bound
// blocks (occupancy 10%). Keep prep as its own light dispatch.
__global__ __launch_bounds__(256) void prep_kernel(const float* __restrict__ qk,
                                                   const float* __restrict__ v,
                                                   half_t* __restrict__ khat,
                                                   half_t* __restrict__ vh,
                                                   float* __restrict__ norm) {
  int g = blockIdx.x * 256 + threadIdx.x;  // over B*S*16
  float4 qv = ((const float4*)qk)[g];
  float4 vv = ((const float4*)v)[g];
  float ss = qv.x * qv.x + qv.y * qv.y + qv.z * qv.z + qv.w * qv.w;
  for (int off = 1; off < 16; off <<= 1) ss += __shfl_xor(ss, off);
  float nr = fmaxf(sqrtf(ss), 1e-12f);
  float sc = 1.0f / nr;
  half4 hk = {(half_t)(qv.x * sc), (half_t)(qv.y * sc), (half_t)(qv.z * sc),
              (half_t)(qv.w * sc)};
  half4 hv = {(half_t)vv.x, (half_t)vv.y, (half_t)vv.z, (half_t)vv.w};
  ((half4*)khat)[g] = hk;
  ((half4*)vh)[g] = hv;
  if ((threadIdx.x & 15) == 0) norm[g >> 4] = nr;
}

// ---------------- Kernel 1: LSH hashing (buckets) ----------------
// Bit-faithful mimic of naive np.einsum float32 (keeps bucket decisions
// identical to the harness reference; per-h summation order over f unchanged:
// fc outer, fi inner, ascending).
// v11 = v9 (R10's best: rounds-interleaved 2-tok pk) + XCD-aware block
// mapping. OLD blk=(b*4+hp)*8+tile put consecutive blocks (same b)
// round-robin over the 8 XCDs -> every XCD touches all 16 batches' qk
// (16.8MB >> 4MB L2) -> all 4 hp-group reads of each qk tile miss at HBM
// latency on the serial unroll-1 critical path (2 waves/SIMD cover). NEW
// b=blk&15 -> XCD=b&7 -> 2 batches = 2.1MB qk per XCD, L2-fits: 3 of 4
// reads become ~200cy L2 hits. Pure index remap (same T1 fix that cut
// chunk FETCH 6x in R9).
// Hash lane history: 1/2/4-tok, scalar/pk, rounds outer/interleaved, coop
// bucket split (R11: -28us regression, 8x redundant q-loads) -- v9 is best.
// Keep __launch_bounds__(256, 1): a (256,2) bound capped VGPR at 128 and
// spilled acc (111MB/dispatch scratch). DO NOT read rot via "uniform" global
// pointers (hipcc does not scalarize: 500us, R1). SINGLE loop nest, no
// fallback branch (old 2-path variant: 6.8GB spill, 3.1ms).
__global__ __launch_bounds__(256, 1) void hash_kernel(const float* __restrict__ qk,
                                                      const float* __restrict__ rot,
                                                      int* __restrict__ bkt) {
  __shared__ float rotS[2 * 2048];  // [hh][f*32+i]
  int tid = threadIdx.x;
  int blk = blockIdx.x;  // b in LOW 4 bits (XCD locality), grid = 512
  int b = blk & 15;
  int r = blk >> 4;  // 0..31
  int hp = r & 3, tile = r >> 2;

  for (int i = tid; i < 4096; i += 256) {
    int hh = i >> 11, rr = i & 2047;
    int f = rr >> 5, ii = rr & 31;
    rotS[i] = rot[(((size_t)b * 64 + f) * 8 + (hp * 2 + hh)) * 32 + ii];
  }
  __syncthreads();

  int t0 = (tile << 9) + tid;  // thread's tokens: t0 + 256*tok, tok=0..1
  const float* qb = qk + (((size_t)b << 12) << 6);

  float2v accA[2][16];  // round hh=0: 16 pairs = 32 buckets per token
  float2v accB[2][16];  // round hh=1
#pragma unroll
  for (int tok = 0; tok < 2; tok++)
#pragma unroll
    for (int i = 0; i < 16; i++) {
      accA[tok][i] = (float2v){0.f, 0.f};
      accB[tok][i] = (float2v){0.f, 0.f};
    }

#pragma unroll 1
  for (int fc = 0; fc < 8; fc++) {
    float q[2][8];
#pragma unroll
    for (int tok = 0; tok < 2; tok++) {
      const float4* qr =
          (const float4*)(qb + ((size_t)(t0 + (tok << 8)) << 6) + fc * 8);
      *(float4*)(q[tok]) = qr[0];
      *(float4*)(q[tok] + 4) = qr[1];
    }
#pragma unroll
    for (int fi = 0; fi < 8; fi++) {
#pragma unroll
      for (int i4 = 0; i4 < 8; i4++) {
        float4 wa = *(const float4*)(rotS + (fc * 8 + fi) * 32 + i4 * 4);
        float4 wb = *(const float4*)(rotS + 2048 + (fc * 8 + fi) * 32 + i4 * 4);
        float2v wa0 = {wa.x, wa.y}, wa1 = {wa.z, wa.w};
        float2v wb0 = {wb.x, wb.y}, wb1 = {wb.z, wb.w};
#pragma unroll
        for (int tok = 0; tok < 2; tok++) {
          float2v q2 = {q[tok][fi], q[tok][fi]};
          float2v p0, p1, p2, p3;
          asm("v_pk_mul_f32 %0, %2, %3\n\t"
              "v_pk_add_f32 %1, %1, %0"
              : "=&v"(p0), "+v"(accA[tok][i4 * 2])
              : "v"(q2), "v"(wa0));
          asm("v_pk_mul_f32 %0, %2, %3\n\t"
              "v_pk_add_f32 %1, %1, %0"
              : "=&v"(p1), "+v"(accA[tok][i4 * 2 + 1])
              : "v"(q2), "v"(wa1));
          asm("v_pk_mul_f32 %0, %2, %3\n\t"
              "v_pk_add_f32 %1, %1, %0"
              : "=&v"(p2), "+v"(accB[tok][i4 * 2])
              : "v"(q2), "v"(wb0));
          asm("v_pk_mul_f32 %0, %2, %3\n\t"
              "v_pk_add_f32 %1, %1, %0"
              : "=&v"(p3), "+v"(accB[tok][i4 * 2 + 1])
              : "v"(q2), "v"(wb1));
        }
      }
    }
  }

#define HASH_ARGMAX(ACC, H)                                              \
  {                                                                      \
    int h = (H);                                                         \
    _Pragma("unroll") for (int tok = 0; tok < 2; tok++) {                \
      float a[32];                                                       \
      _Pragma("unroll") for (int p = 0; p < 16; p++) {                   \
        a[2 * p] = ACC[tok][p].x;                                        \
        a[2 * p + 1] = ACC[tok][p].y;                                    \
      }                                                                  \
      float b1 = a[0];                                                   \
      int i1 = 0;                                                        \
      _Pragma("unroll") for (int i = 1; i < 32; i++) if (a[i] > b1) {    \
        b1 = a[i];                                                       \
        i1 = i;                                                          \
      }                                                                  \
      _Pragma("unroll") for (int i = 0; i < 32; i++) {                   \
        float x = -a[i];                                                 \
        if (x > b1) {                                                    \
          b1 = x;                                                        \
          i1 = 32 + i;                                                   \
        }                                                                \
      }                                                                  \
      bkt[(((size_t)(b * 8 + h)) << 12) + t0 + (tok << 8)] = i1;         \
    }                                                                    \
  }

  HASH_ARGMAX(accA, hp * 2)
  HASH_ARGMAX(accB, hp * 2 + 1)
#undef HASH_ARGMAX
}

// ---------------- Kernel 2: stable counting sort per (b,h) ----------------
// v2: 1024 threads/block (neutral vs 256, kept).
__global__ __launch_bounds__(1024) void sort_kernel(const int* __restrict__ bkt,
                                                    int* __restrict__ st) {
  __shared__ int lb[4096];
  __shared__ int hist[4096];  // [chunk(64)][bucket(64)]
  __shared__ int cumoff[64];
  int tid = threadIdx.x;
  int b = blockIdx.x >> 3, h = blockIdx.x & 7;
  const int* gb = bkt + (((size_t)(b * 8 + h)) << 12);
  for (int t = tid; t < 4096; t += 1024) lb[t] = gb[t];
  for (int i = tid; i < 4096; i += 1024) hist[i] = 0;
  __syncthreads();
  for (int t = tid; t < 4096; t += 1024) atomicAdd(&hist[((t >> 6) << 6) | lb[t]], 1);
  __syncthreads();
  if (tid < 64) {
    int run = 0;
    for (int cc = 0; cc < 64; cc++) {
      int x = hist[(cc << 6) | tid];
      hist[(cc << 6) | tid] = run;
      run += x;
    }
    // exclusive prefix over buckets via wave-0 shfl scan
    int s = run;
    for (int off = 1; off < 64; off <<= 1) {
      int u = __shfl_up(s, off);
      if (tid >= off) s += u;
    }
    cumoff[tid] = s - run;
  }
  __syncthreads();
  int lane = tid & 63;
  for (int p = 0; p < 4; p++) {
    int t = (p << 10) + tid;  // each wave covers one aligned 64-token chunk
    int vb = lb[t];
    unsigned long long m = 0xFFFFFFFFFFFFFFFFull;
#pragma unroll
    for (int bit = 0; bit < 6; bit++) {
      unsigned long long bl = __ballot((vb >> bit) & 1);
      m &= ((vb >> bit) & 1) ? bl : ~bl;
    }
    int rank = __popcll(m & ((1ull << lane) - 1ull));
    int cpos = cumoff[vb] + hist[((t >> 6) << 6) | vb] + rank;
    st[(((size_t)(b * 8 + h)) << 12) + cpos] = t;
  }
}

// ---------------- Kernel 3: fused chunk kernel ----------------
// Per (b, round, chunk): QK^T (MFMA) -> per-round softmax -> P.V (MFMA),
// write normalized per-round output o_r (fp16) + lse_r. No atomics.
// grid: B*512 blocks, 256 threads = 4 waves. Measured 70.9us (R10).
// v6: XCD-aware block mapping (T1): b in low 4 bits -> XCD = b&7 -> per-XCD
// 2-batch L2 tile (2.1MB fits 4MB L2). CONFIRMED on counters: FETCH 62->11MB.
// Time only -2us -> gathers were not the critical path; this kernel has
// resisted 5 orthogonal probes (VALU cut, occupancy, direct stores, barrier
// cuts, L2 fix) at ~71-74us. Do not churn without a new counter signal.
// R6's direct-2B-store epilogue REGRESSED (74->81): keep O->LDS->b128.
// v3: structural self-mask (st is a permutation: current-chunk self-match is
// key_idx==row_idx, nt==w uniform; look-back needs token compares only for
// the 8 c==0 chunks); exp2-domain softmax (MASK2 = -50000*log2e).
// v2: single-exp softmax, both V halves staged up front; the P-write ->
// pfr-read hop is intra-wave only (wave w writes/reads P rows [16w,16w+16)),
// no barrier there.
#define MASK2 -72134.76f
__global__ __launch_bounds__(256) void chunk_kernel(const half_t* __restrict__ khat,
                                                    const half_t* __restrict__ vh,
                                                    const float* __restrict__ norm,
                                                    const int* __restrict__ st,
                                                    half_t* __restrict__ oh,
                                                    float* __restrict__ lse) {
  __shared__ __align__(16) half_t Ks[128 * KSTR];  // K; later P (64 rows, PSTR)
  __shared__ __align__(16) half_t Vt0[64 * VSTR];  // V^T keys 0..63; later O
  __shared__ __align__(16) half_t Vt1[64 * VSTR];  // V^T keys 64..127
  __shared__ int tk[128];
  __shared__ float normS[64];
  int tid = threadIdx.x;
  // XCD swizzle: b in low 4 bits -> XCD = b & 7 -> per-XCD 2-batch L2 tile
  int b = blockIdx.x & 15;
  int g = blockIdx.x >> 4;
  int h = g >> 6, c = g & 63;
  int gp = (g + 511) & 511;
  int hp = gp >> 6, cp = gp & 63;
  if (tid < 64) {
    tk[tid] = st[(((size_t)(b * 8 + h)) << 12) + (c << 6) + tid];
  } else if (tid < 128) {
    tk[tid] = st[(((size_t)(b * 8 + hp)) << 12) + (cp << 6) + (tid - 64)];
  }
  __syncthreads();
  if (tid < 64) normS[tid] = norm[(b << 12) + tk[tid]];
  // stage K (128 rows): single b128 load -> single b128 LDS store
  for (int idx = tid; idx < 1024; idx += 256) {
    int row = idx >> 3, fo = idx & 7;
    half8 val = *(const half8*)(khat + (((size_t)(b << 12) + tk[row]) << 6) + fo * 8);
    *(half8*)(Ks + row * KSTR + fo * 8) = val;
  }
  // stage BOTH V halves transposed (all gathers in flight together)
  {
    int kp = tid & 31, ch = tid >> 5;  // ch in 0..7
    half8 r0 = *(const half8*)(vh + (((size_t)(b << 12) + tk[2 * kp]) << 6) + ch * 8);
    half8 r1 = *(const half8*)(vh + (((size_t)(b << 12) + tk[2 * kp + 1]) << 6) + ch * 8);
    half8 r2 = *(const half8*)(vh + (((size_t)(b << 12) + tk[64 + 2 * kp]) << 6) + ch * 8);
    half8 r3 = *(const half8*)(vh + (((size_t)(b << 12) + tk[65 + 2 * kp]) << 6) + ch * 8);
#pragma unroll
    for (int j = 0; j < 8; j++) {
      half2t p0 = {r0[j], r1[j]};
      half2t p1 = {r2[j], r3[j]};
      *(half2t*)(Vt0 + (ch * 8 + j) * VSTR + 2 * kp) = p0;
      *(half2t*)(Vt1 + (ch * 8 + j) * VSTR + 2 * kp) = p1;
    }
  }
  __syncthreads();

  int lane = tid & 63, w = tid >> 6;
  int m = lane & 15, quad = lane >> 4;
  half8 afr[2];
#pragma unroll
  for (int ki = 0; ki < 2; ki++)
    afr[ki] = *(const half8*)(Ks + (w * 16 + m) * KSTR + ki * 32 + quad * 8);
  bool c0 = (c == 0);
  float scr[4];
#pragma unroll
  for (int r = 0; r < 4; r++) {
    int rr = w * 16 + quad * 4 + r;
    scr[r] = 0.18033688f * normS[rr];  // 0.125 * log2(e)
  }
  int ti[4] = {0, 0, 0, 0};
  if (c0) {
#pragma unroll
    for (int r = 0; r < 4; r++) ti[r] = tk[w * 16 + quad * 4 + r];
  }

  // QK^T dots (log2 domain), masked + scaled
  float d[8][4];
#pragma unroll
  for (int nt = 0; nt < 8; nt++) {
    floatx4 acc = {0.f, 0.f, 0.f, 0.f};
#pragma unroll
    for (int ki = 0; ki < 2; ki++) {
      half8 bfr = *(const half8*)(Ks + (nt * 16 + m) * KSTR + ki * 32 + quad * 8);
      acc = __builtin_amdgcn_mfma_f32_16x16x32_f16(afr[ki], bfr, acc, 0, 0, 0);
    }
    if (nt < 4) {
      // current-chunk keys: self-match iff key_idx == row_idx (permutation)
      if (nt == w) {
#pragma unroll
        for (int r = 0; r < 4; r++)
          d[nt][r] = (m == quad * 4 + r) ? MASK2 : acc[r] * scr[r];
      } else {
#pragma unroll
        for (int r = 0; r < 4; r++) d[nt][r] = acc[r] * scr[r];
      }
    } else {
      // look-back keys: same-round prev chunk (c>0) has distinct tokens
      if (c0) {
        int tj = tk[nt * 16 + m];
#pragma unroll
        for (int r = 0; r < 4; r++)
          d[nt][r] = (ti[r] == tj) ? MASK2 : acc[r] * scr[r];
      } else {
#pragma unroll
        for (int r = 0; r < 4; r++) d[nt][r] = acc[r] * scr[r];
      }
    }
  }

  // per-round row softmax (log2 domain): max, exp2 once in place, sum
  float mr4[4], lr4[4];
#pragma unroll
  for (int r = 0; r < 4; r++) {
    float mm = d[0][r];
#pragma unroll
    for (int nt = 1; nt < 8; nt++) mm = fmaxf(mm, d[nt][r]);
    for (int off = 1; off < 16; off <<= 1) mm = fmaxf(mm, __shfl_xor(mm, off));
    mr4[r] = mm;
  }
#pragma unroll
  for (int nt = 0; nt < 8; nt++)
#pragma unroll
    for (int r = 0; r < 4; r++)
      d[nt][r] = __builtin_amdgcn_exp2f(d[nt][r] - mr4[r]);
#pragma unroll
  for (int r = 0; r < 4; r++) {
    float ll = 0.f;
#pragma unroll
    for (int nt = 0; nt < 8; nt++) ll += d[nt][r];
    for (int off = 1; off < 16; off <<= 1) ll += __shfl_xor(ll, off);
    lr4[r] = ll;
    if (m == 0) {
      int rr = w * 16 + quad * 4 + r;
      lse[(((size_t)(b * 8 + h)) << 12) + tk[rr]] =
          0.69314718f * (mr4[r] + __builtin_amdgcn_logf(ll));
    }
  }
  __syncthreads();  // all waves done reading Ks as K

  // P' = exp2(d - m_r) fp16 into Ks region (stride PSTR); values already in d
  half_t* Ps = Ks;
#pragma unroll
  for (int nt = 0; nt < 8; nt++) {
#pragma unroll
    for (int r = 0; r < 4; r++) {
      Ps[(w * 16 + quad * 4 + r) * PSTR + nt * 16 + m] = (half_t)d[nt][r];
    }
  }
  // intra-wave RAW only (own 16 rows) -> compiler-ordered via lgkmcnt, no barrier

  half8 pfr[4];
#pragma unroll
  for (int kk = 0; kk < 4; kk++)
    pfr[kk] = *(const half8*)(Ps + (w * 16 + m) * PSTR + kk * 32 + quad * 8);

  floatx4 accO[4];
#pragma unroll
  for (int dt = 0; dt < 4; dt++) accO[dt] = (floatx4){0.f, 0.f, 0.f, 0.f};

  // PV over all 128 keys, contiguous MFMA cluster
#pragma unroll
  for (int dt = 0; dt < 4; dt++) {
#pragma unroll
    for (int kk = 0; kk < 2; kk++) {
      half8 bfr = *(const half8*)(Vt0 + (dt * 16 + m) * VSTR + kk * 32 + quad * 8);
      accO[dt] = __builtin_amdgcn_mfma_f32_16x16x32_f16(pfr[kk], bfr, accO[dt], 0, 0, 0);
    }
#pragma unroll
    for (int kk = 2; kk < 4; kk++) {
      half8 bfr = *(const half8*)(Vt1 + (dt * 16 + m) * VSTR + (kk - 2) * 32 + quad * 8);
      accO[dt] = __builtin_amdgcn_mfma_f32_16x16x32_f16(pfr[kk], bfr, accO[dt], 0, 0, 0);
    }
  }
  __syncthreads();  // all Vt0 reads done; reuse Vt0 for O

  // normalized O (fp16) -> LDS, then coalesced 16B row stores
  half_t* Ot = Vt0;
#pragma unroll
  for (int r = 0; r < 4; r++) {
    float inv = 1.0f / lr4[r];
#pragma unroll
    for (int dt = 0; dt < 4; dt++) {
      Ot[(w * 16 + quad * 4 + r) * VSTR + dt * 16 + m] = (half_t)(accO[dt][r] * inv);
    }
  }
  __syncthreads();
  for (int idx = tid; idx < 512; idx += 256) {
    int row = idx >> 3, fo = idx & 7;
    half8 val = *(const half8*)(Ot + row * VSTR + fo * 8);
    *(half8*)(oh + ((((size_t)(b * 8 + h)) << 12) + tk[row]) * 64 + fo * 8) = val;
  }
}

// ---------------- Kernel 4: combine rounds ----------------
// out[b,t,:] = sum_r exp(lse_r - lse_tot) * o_r[b,t,:]
// grid: B*S*8/256 blocks; thread = (token, 8-dim group)
__global__ __launch_bounds__(256) void combine_kernel(const half_t* __restrict__ oh,
                                                      const float* __restrict__ lse,
                                                      float* __restrict__ out) {
  int idx = blockIdx.x * 256 + threadIdx.x;  // over B*S*8
  int do8 = idx & 7;
  int ts = idx >> 3;  // b*4096 + t
  int b = ts >> 12, t = ts & 4095;
  size_t base = ((size_t)b << 15) + t;  // (b*8)<<12 + t
  float L[8];
  float m = -3.4e38f;
#pragma unroll
  for (int h = 0; h < 8; h++) {
    L[h] = lse[base + ((size_t)h << 12)];
    m = fmaxf(m, L[h]);
  }
  float s = 0.f;
#pragma unroll
  for (int h = 0; h < 8; h++) s += __expf(L[h] - m);
  float lt = m + __logf(s);
  float acc[8];
#pragma unroll
  for (int j = 0; j < 8; j++) acc[j] = 0.f;
#pragma unroll
  for (int h = 0; h < 8; h++) {
    float wgt = __expf(L[h] - lt);
    half8 o = *(const half8*)(oh + ((base + ((size_t)h << 12)) << 6) + do8 * 8);
#pragma unroll
    for (int j = 0; j < 8; j++) acc[j] += wgt * (float)o[j];
  }
  float* dst = out + ((((size_t)b << 12) + t) << 6) + do8 * 8;
  *(float4*)dst = (float4){acc[0], acc[1], acc[2], acc[3]};
  *(float4*)(dst + 4) = (float4){acc[4], acc[5], acc[6], acc[7]};
}

extern "C" void kernel_launch(void* const* d_in, const int* in_sizes, int n_in,
                              void* d_out, int out_size, void* d_ws, size_t ws_size,
                              hipStream_t stream) {
  const float* qk = (const float*)d_in[0];
  const float* v = (const float*)d_in[1];
  const float* rot = (const float*)d_in[2];
  float* out = (float*)d_out;

  int* bkt = (int*)d_ws;                            // 2MB
  int* stp = bkt + NB_B * NB_H * NB_S;              // 2MB
  float* lse = (float*)(stp + NB_B * NB_H * NB_S);  // 2MB
  float* norm = lse + NB_B * NB_H * NB_S;           // 256KB
  half_t* khat = (half_t*)(norm + NB_B * NB_S);     // 8MB
  half_t* vh = khat + (size_t)NB_B * NB_S * NB_D;   // 8MB
  half_t* oh = vh + (size_t)NB_B * NB_S * NB_D;     // B*H*S*D fp16 = 67MB

  prep_kernel<<<NB_B * NB_S * 16 / 256, 256, 0, stream>>>(qk, v, khat, vh, norm);
  hash_kernel<<<512, 256, 0, stream>>>(qk, rot, bkt);
  sort_kernel<<<NB_B * NB_H, 1024, 0, stream>>>(bkt, stp);
  chunk_kernel<<<NB_B * 512, 256, 0, stream>>>(khat, vh, norm, stp, oh, lse);
  combine_kernel<<<NB_B * NB_S * 8 / 256, 256, 0, stream>>>(oh, lse, out);
}